// Round 6
// baseline (219.347 us; speedup 1.0000x reference)
//
#include <hip/hip_runtime.h>
#include <math.h>

#define HH 256
#define WW 256
#define BB 8
#define MM 256
#define NN (HH * WW)
#define TPB 256
#define BLKS_PER_B HH                     // one row per block -> 256
#define NBLK (BB * BLKS_PER_B)            // 2048 blocks = 8/CU = 8 waves/SIMD

#define EPSI 1e-6f
#define MAXD 362.03867196751236f
#define EPS_OVER_MAXD (1e-6f / 362.03867196751236f)

static __device__ __forceinline__ float asqrt(float x) {
    return __builtin_amdgcn_sqrtf(x);     // single v_sqrt_f32
}

// ws layout (uints): [0..15] counter | [16..16+2047] gmin (INVERTED float
// bits: 0 == +inf under unsigned atomicMax) | [2064..2064+4095] per-block
// partial sums (s0, s1) per block.
__global__ __launch_bounds__(256, 8) void whd_fused(
    const float* __restrict__ pm, const float* __restrict__ gt,
    const float* __restrict__ osz, float* __restrict__ out,
    unsigned* __restrict__ ws0)
{
    unsigned* ctr  = ws0;
    unsigned* gmin = ws0 + 16;                 // BB*MM
    unsigned* part = ws0 + 16 + BB * MM;       // NBLK*2

    __shared__ __align__(16) float2 sge[MM];   // (gx_scaled, ey=(y-gy)^2) per m
    __shared__ __align__(16) float2 ssc[WW];   // (sc, EPSI*sc) per pixel col
    __shared__ float swred[8];
    __shared__ float tsum[BB];
    __shared__ float gred[4];
    __shared__ int   lastFlag;

    const int tid = threadIdx.x;
    const int blk = blockIdx.x;   // row 0..255
    const int b   = blockIdx.y;

    const float nfY = osz[b * 2 + 0] * (1.0f / HH);
    const float nfX = osz[b * 2 + 1] * (1.0f / WW);
    const float y   = (float)blk * nfY;        // block-uniform row coord

    // ---- staging: thread tid handles GT point m=tid and pixel col=tid
    const float2 g  = ((const float2*)gt)[b * MM + tid];
    const float  gx = g.y * nfX;               // scaled GT x
    const float  dy = y - g.x * nfY;
    const float  ey = dy * dy;                 // (y - gy)^2, block-uniform row
    sge[tid] = make_float2(gx, ey);

    const float p  = pm[b * NN + blk * WW + tid];
    const float p2 = p * p;
    const float sc = 1.0f / (p2 * p2 + EPS_OVER_MAXD);   // 1/(p^4 + EPS/MAXD)
    ssc[tid] = make_float2(sc, EPSI * sc);
    __syncthreads();

    // ---- Phase A: pixel col=tid; min_m d^2. 3 VALU/pair, b128 reads,
    // 2 accumulators, no atomics/shuffles.
    const float x = (float)tid * nfX;
    float minA = INFINITY, minB = INFINITY;
    const float4* sge4 = (const float4*)sge;
    #pragma unroll 8
    for (int k = 0; k < MM / 2; ++k) {
        const float4 gg = sge4[k];             // (gx0, ey0, gx1, ey1)
        const float dx0 = x - gg.x;
        const float dx1 = x - gg.z;
        minA = fminf(minA, fmaf(dx0, dx0, gg.y));
        minB = fminf(minB, fmaf(dx1, dx1, gg.w));
    }
    const float mind2 = fminf(minA, minB);

    // ---- Phase B: m=tid (gx, ey live in registers); min over this row's
    // 256 pixels of (sqrt(d2)+EPS)*sc. 2 px per b128 read, incremental dx.
    float cmA = INFINITY, cmB = INFINITY;
    const float4* ssc4 = (const float4*)ssc;
    float dxA = 0.0f - gx;
    float dxB = nfX - gx;
    const float step = 2.0f * nfX;
    #pragma unroll 8
    for (int k = 0; k < WW / 2; ++k) {
        const float4 s  = ssc4[k];             // (sc0, c40, sc1, c41)
        const float dA  = fmaf(dxA, dxA, ey);
        const float dB  = fmaf(dxB, dxB, ey);
        cmA = fminf(cmA, fmaf(asqrt(dA), s.x, s.y));
        cmB = fminf(cmB, fmaf(asqrt(dB), s.z, s.w));
        dxA += step;
        dxB += step;
    }
    const float cmin = fminf(cmA, cmB);

    // ---- term1 partials (thread-exclusive pixel)
    float sum0 = p;
    float sum1 = p * asqrt(mind2);
    #pragma unroll
    for (int off = 32; off; off >>= 1) {
        sum0 += __shfl_down(sum0, off, 64);
        sum1 += __shfl_down(sum1, off, 64);
    }
    if ((tid & 63) == 0) { swred[(tid >> 6) * 2] = sum0; swred[(tid >> 6) * 2 + 1] = sum1; }
    __syncthreads();

    const int blin = b * BLKS_PER_B + blk;
    if (tid == 0) {
        const float s0 = (swred[0] + swred[2]) + (swred[4] + swred[6]);
        const float s1 = (swred[1] + swred[3]) + (swred[5] + swred[7]);
        atomicExch(&part[blin * 2 + 0], __float_as_uint(s0));
        atomicExch(&part[blin * 2 + 1], __float_as_uint(s1));
    }
    // merge this block's per-m column min into global (inverted bits -> max)
    atomicMax(&gmin[b * MM + tid], ~__float_as_uint(cmin));

    // ---- last-block combine
    __threadfence();
    if (tid == 0) lastFlag = (atomicAdd(ctr, 1u) == NBLK - 1);
    __syncthreads();
    if (!lastFlag) return;
    __threadfence();

    // term2: mean of clipped per-(b,m) minima
    float gacc = 0.0f;
    #pragma unroll
    for (int q = 0; q < BB; ++q) {
        const float v = __uint_as_float(~atomicOr(&gmin[q * MM + tid], 0u));
        gacc += fminf(fmaxf(v, 0.0f), MAXD);
    }
    #pragma unroll
    for (int off = 32; off; off >>= 1) gacc += __shfl_down(gacc, off, 64);
    if ((tid & 63) == 0) gred[tid >> 6] = gacc;

    // term1: per-batch ratios from per-block partials (8 batches x 32 lanes)
    {
        const int bb = tid >> 5, r = tid & 31;
        float s0 = 0.0f, s1 = 0.0f;
        #pragma unroll
        for (int q = 0; q < BLKS_PER_B / 32; ++q) {   // 8
            const int bl = bb * BLKS_PER_B + r + q * 32;
            s0 += __uint_as_float(atomicOr(&part[bl * 2 + 0], 0u));
            s1 += __uint_as_float(atomicOr(&part[bl * 2 + 1], 0u));
        }
        #pragma unroll
        for (int off = 16; off; off >>= 1) {
            s0 += __shfl_down(s0, off, 32);
            s1 += __shfl_down(s1, off, 32);
        }
        if (r == 0) tsum[bb] = s1 / (s0 + EPSI);
    }
    __syncthreads();
    if (tid == 0) {
        float t1 = 0.0f;
        #pragma unroll
        for (int q = 0; q < BB; ++q) t1 += tsum[q];
        const float g2 = (gred[0] + gred[1]) + (gred[2] + gred[3]);
        out[0] = t1 * (1.0f / BB) + g2 * (1.0f / (BB * MM));
    }
}

extern "C" void kernel_launch(void* const* d_in, const int* in_sizes, int n_in,
                              void* d_out, int out_size, void* d_ws, size_t ws_size,
                              hipStream_t stream) {
    const float* pm  = (const float*)d_in[0];   // [B, H, W]
    const float* gt  = (const float*)d_in[1];   // [B, M, 2]
    const float* osz = (const float*)d_in[2];   // [B, 2]
    float* out = (float*)d_out;
    unsigned* ws0 = (unsigned*)d_ws;

    // counter + gmin zero-init (gmin inverted bits: 0 == +inf)
    hipMemsetAsync(ws0, 0, (16 + BB * MM) * sizeof(unsigned), stream);

    dim3 grid(BLKS_PER_B, BB);
    whd_fused<<<grid, 256, 0, stream>>>(pm, gt, osz, out, ws0);
}

// Round 7
// 103.344 us; speedup vs baseline: 2.1225x; 2.1225x over previous
//
#include <hip/hip_runtime.h>
#include <math.h>

#define HH 256
#define WW 256
#define BB 8
#define MM 256
#define NN (HH * WW)
#define ROWS 2
#define BLKS_PER_B (HH / ROWS)            // 128 -> grid 1024 = 4 blocks/CU

#define EPSI 1e-6f
#define MAXD 362.03867196751236f
#define EPS_OVER_MAXD (1e-6f / 362.03867196751236f)

static __device__ __forceinline__ float asqrt(float x) {
    return __builtin_amdgcn_sqrtf(x);     // single v_sqrt_f32
}

// ws layout (u32): [0..15] sums (float: s0,s1 per batch, 2*BB used)
//                  [16..16+BB*MM) gmin, INVERTED float bits (0 == +inf)
__global__ __launch_bounds__(256, 4) void whd_main(
    const float* __restrict__ pm, const float* __restrict__ gt,
    const float* __restrict__ osz, float* __restrict__ sums,
    unsigned* __restrict__ gmin)
{
    __shared__ __align__(16) float4 sge[MM];   // (gx, ey_row0, ey_row1, -) per m
    __shared__ __align__(16) float4 ssc[WW];   // (sc0, eps*sc0, sc1, eps*sc1) per col
    __shared__ float swred[8];

    const int tid = threadIdx.x;
    const int blk = blockIdx.x;   // 0..127
    const int b   = blockIdx.y;

    const float nfY = osz[b * 2 + 0] * (1.0f / HH);
    const float nfX = osz[b * 2 + 1] * (1.0f / WW);
    const int   r0  = blk * ROWS, r1 = r0 + 1;
    const float y0  = (float)r0 * nfY;
    const float y1  = (float)r1 * nfY;

    // ---- staging: thread tid owns GT point m=tid and pixel column col=tid
    const float2 g  = ((const float2*)gt)[b * MM + tid];
    const float  gx = g.y * nfX;
    const float  gy = g.x * nfY;
    const float  dy0 = y0 - gy, dy1 = y1 - gy;
    const float  ey0 = dy0 * dy0, ey1 = dy1 * dy1;   // stay in regs for phase B
    sge[tid] = make_float4(gx, ey0, ey1, 0.0f);

    const float p0 = pm[b * NN + r0 * WW + tid];     // coalesced
    const float p1 = pm[b * NN + r1 * WW + tid];
    const float q0 = p0 * p0, q1 = p1 * p1;
    const float sc0 = 1.0f / (q0 * q0 + EPS_OVER_MAXD);   // 1/(p^4 + EPS/MAXD)
    const float sc1 = 1.0f / (q1 * q1 + EPS_OVER_MAXD);
    ssc[tid] = make_float4(sc0, EPSI * sc0, sc1, EPSI * sc1);
    __syncthreads();

    // ---- Phase A: pixel col=tid, rows r0,r1; min_m d^2. dx shared across
    // rows; uniform broadcast reads; 4 independent fmin chains; no atomics.
    const float x = (float)tid * nfX;
    float mA0 = INFINITY, mA1 = INFINITY;   // row0 chains
    float mB0 = INFINITY, mB1 = INFINITY;   // row1 chains
    #pragma unroll 4
    for (int m = 0; m < MM; m += 2) {
        const float4 g0 = sge[m];
        const float4 g1 = sge[m + 1];
        const float dxa = x - g0.x;
        const float dxb = x - g1.x;
        mA0 = fminf(mA0, fmaf(dxa, dxa, g0.y));
        mB0 = fminf(mB0, fmaf(dxa, dxa, g0.z));
        mA1 = fminf(mA1, fmaf(dxb, dxb, g1.y));
        mB1 = fminf(mB1, fmaf(dxb, dxb, g1.z));
    }
    const float mind2r0 = fminf(mA0, mA1);
    const float mind2r1 = fminf(mB0, mB1);

    // ---- Phase B: thread owns m=tid (gx/ey0/ey1 in regs); min over the
    // block's 512 pixels of (sqrt(d2)+EPS)*sc. dx shared across rows,
    // incremental; uniform broadcast reads; no atomics in loop.
    float cm0 = INFINITY, cm1 = INFINITY;
    float dx  = 0.0f - gx;
    #pragma unroll 8
    for (int c = 0; c < WW; ++c) {
        const float4 s = ssc[c];
        const float d0 = fmaf(dx, dx, ey0);
        const float d1 = fmaf(dx, dx, ey1);
        cm0 = fminf(cm0, fmaf(asqrt(d0), s.x, s.y));
        cm1 = fminf(cm1, fmaf(asqrt(d1), s.z, s.w));
        dx += nfX;
    }
    const float cmin = fminf(cm0, cm1);

    // ---- term1 partials (thread-exclusive pixels), one wave reduce
    float sum0 = p0 + p1;
    float sum1 = fmaf(p0, asqrt(mind2r0), p1 * asqrt(mind2r1));
    #pragma unroll
    for (int off = 32; off; off >>= 1) {
        sum0 += __shfl_down(sum0, off, 64);
        sum1 += __shfl_down(sum1, off, 64);
    }
    if ((tid & 63) == 0) { swred[(tid >> 6) * 2] = sum0; swred[(tid >> 6) * 2 + 1] = sum1; }
    __syncthreads();

    // fire-and-forget merges only — no fence, no counter, no waiting
    if (tid == 0) {
        const float s0 = (swred[0] + swred[2]) + (swred[4] + swred[6]);
        const float s1 = (swred[1] + swred[3]) + (swred[5] + swred[7]);
        atomicAdd(&sums[b * 2 + 0], s0);
        atomicAdd(&sums[b * 2 + 1], s1);
    }
    atomicMax(&gmin[b * MM + tid], ~__float_as_uint(cmin));
}

// ---------------------------------------------------------------------------
__global__ __launch_bounds__(256) void whd_final(const float* __restrict__ sums,
                                                 const unsigned* __restrict__ gmin,
                                                 float* __restrict__ out) {
    __shared__ float gred[4];
    const int tid = threadIdx.x;

    float gacc = 0.0f;
    #pragma unroll
    for (int q = 0; q < BB; ++q) {
        const float v = __uint_as_float(~gmin[q * MM + tid]);
        gacc += fminf(fmaxf(v, 0.0f), MAXD);
    }
    #pragma unroll
    for (int off = 32; off; off >>= 1) gacc += __shfl_down(gacc, off, 64);
    if ((tid & 63) == 0) gred[tid >> 6] = gacc;
    __syncthreads();
    if (tid == 0) {
        float t1 = 0.0f;
        #pragma unroll
        for (int q = 0; q < BB; ++q)
            t1 += sums[q * 2 + 1] / (sums[q * 2 + 0] + EPSI);
        const float g2 = (gred[0] + gred[1]) + (gred[2] + gred[3]);
        out[0] = t1 * (1.0f / BB) + g2 * (1.0f / (BB * MM));
    }
}

// ---------------------------------------------------------------------------
extern "C" void kernel_launch(void* const* d_in, const int* in_sizes, int n_in,
                              void* d_out, int out_size, void* d_ws, size_t ws_size,
                              hipStream_t stream) {
    const float* pm  = (const float*)d_in[0];   // [B, H, W]
    const float* gt  = (const float*)d_in[1];   // [B, M, 2]
    const float* osz = (const float*)d_in[2];   // [B, 2]
    float* out = (float*)d_out;

    float*    sums = (float*)d_ws;                      // 16 floats
    unsigned* gmin = (unsigned*)d_ws + 16;              // BB*MM entries

    // zero-init: sums = 0.0f, gmin = 0 (== +inf in inverted representation)
    hipMemsetAsync(d_ws, 0, (16 + BB * MM) * sizeof(unsigned), stream);

    dim3 grid(BLKS_PER_B, BB);
    whd_main<<<grid, 256, 0, stream>>>(pm, gt, osz, sums, gmin);
    whd_final<<<1, 256, 0, stream>>>(sums, gmin, out);
}